// Round 6
// baseline (440.089 us; speedup 1.0000x reference)
//
#include <hip/hip_runtime.h>
#include <math.h>

// WaveRNN: B=4096, T=2048, H=5 tanh RNN + fc1(5x5)+relu + fc2(1x5), fused.
// One batch element per 8-lane group (H padded 5->8 with zero rows); lane j
// owns h_j; cross-lane exchange via ds_swizzle XOR patterns. One swizzle set
// of h_new serves both fc1 at step t and the W_hh dot at step t+1.
//
// Precision: the 2048-step tanh chain amplifies per-step rounding ~5e4x.
// Round-2 fast_tanh (~1e-6/step) gave absmax 0.064 > 0.043. This version:
// compensated exp2 argument + Newton-refined rcp -> ~1.5e-7/step.

#define B_ 4096
#define T_ 2048

#define SWZF(v, pat) __int_as_float(__builtin_amdgcn_ds_swizzle(__float_as_int(v), (pat)))
#define XOR1 ((1 << 10) | 0x1F)
#define XOR2 ((2 << 10) | 0x1F)
#define XOR3 ((3 << 10) | 0x1F)
#define XOR4 ((4 << 10) | 0x1F)
#define XOR5 ((5 << 10) | 0x1F)
#define XOR6 ((6 << 10) | 0x1F)
#define XOR7 ((7 << 10) | 0x1F)

__device__ __forceinline__ float precise_tanh(float x) {
    // tanh(x) = 1 - 2/(exp2(2x*log2e)+1), with compensated argument and
    // Newton-refined reciprocal. Branchless. |x| clamped to 15 (tanh==+-1
    // in f32 beyond ~9.01) so E stays finite and Newton never sees inf.
    const float L_hi = 1.44269504f;        // log2(e) rounded to f32
    const float L_lo = 1.9259630e-8f;      // log2(e) - L_hi
    const float LN2  = 0.69314718f;

    float xc = fminf(fmaxf(x, -15.0f), 15.0f);   // v_med3-able
    float y2 = xc + xc;
    float a  = y2 * L_hi;
    float dl = fmaf(y2, L_hi, -a);               // product rounding (exact via fma)
    dl = fmaf(y2, L_lo, dl);                     // + tail of log2e
    float e0 = __builtin_amdgcn_exp2f(a);        // hw v_exp_f32, <=1 ulp
    float e  = fmaf(e0, dl * LN2, e0);           // E = e0*(1 + dl*ln2)
    float d  = e + 1.0f;
    float r0 = __builtin_amdgcn_rcpf(d);
    float r  = fmaf(fmaf(-d, r0, 1.0f), r0, r0); // one Newton step: ~1 ulp
    return fmaf(-2.0f, r, 1.0f);
}

__global__ __launch_bounds__(64, 1) void wavernn_kernel(
    const float* __restrict__ hidden, const float* __restrict__ X,
    const float* __restrict__ W_ih, const float* __restrict__ W_hh,
    const float* __restrict__ b_ih, const float* __restrict__ b_hh,
    const float* __restrict__ fc1_w, const float* __restrict__ fc1_b,
    const float* __restrict__ fc2_w, const float* __restrict__ fc2_b,
    float* __restrict__ out)
{
    const int lane = threadIdx.x;                    // 0..63
    const int j = lane & 7;                          // position in 8-lane group
    const int grp = (blockIdx.x * 64 + lane) >> 3;   // batch element, 0..4095

    // Per-lane weights, XOR-indexed: w[k] pairs with the value from lane j^k.
    float w[8], f[8];
#pragma unroll
    for (int k = 0; k < 8; ++k) {
        const int c = j ^ k;
        const bool live = (j < 5) && (c < 5);
        w[k] = live ? W_hh[j * 5 + c] : 0.0f;    // h_new[j] += W_hh[j][c] * h[c]
        f[k] = live ? fc1_w[j * 5 + c] : 0.0f;   // hid[j]  += fc1_w[j][c] * h[c]
    }
    const float wih  = (j < 5) ? W_ih[j] : 0.0f;
    const float bias = (j < 5) ? (b_ih[j] + b_hh[j]) : 0.0f;
    const float fb   = (j < 5) ? fc1_b[j] : 0.0f;
    const float w2   = (j < 5) ? fc2_w[j] : 0.0f;
    const float b2   = fc2_b[0];

    float h = (j < 5) ? hidden[grp * 5 + j] : 0.0f;  // hidden is [1,B,H]

    // r[k] = h from lane j^k (group-local). r persists across steps.
    float r[8];
    r[0] = h;
    r[1] = SWZF(h, XOR1); r[2] = SWZF(h, XOR2); r[3] = SWZF(h, XOR3);
    r[4] = SWZF(h, XOR4); r[5] = SWZF(h, XOR5); r[6] = SWZF(h, XOR6);
    r[7] = SWZF(h, XOR7);

    const float* __restrict__ xrow = X  + (size_t)grp * T_;   // X is [B,T,1]
    float*       __restrict__ yrow = out + (size_t)grp * T_;  // y is [B,T,1]

    for (int t = 0; t < T_; t += 4) {
        const float4 x4 = *reinterpret_cast<const float4*>(xrow + t);
        float y0, y1, y2, y3;
#pragma unroll
        for (int u = 0; u < 4; ++u) {
            const float x = (u == 0) ? x4.x : (u == 1) ? x4.y : (u == 2) ? x4.z : x4.w;

            // acc = x*W_ih[j] + (b_ih+b_hh)[j] + sum_c W_hh[j][c] * h_prev[c]
            float acc = fmaf(x, wih, bias);
            acc = fmaf(w[0], r[0], acc); acc = fmaf(w[1], r[1], acc);
            acc = fmaf(w[2], r[2], acc); acc = fmaf(w[3], r[3], acc);
            acc = fmaf(w[4], r[4], acc); acc = fmaf(w[5], r[5], acc);
            acc = fmaf(w[6], r[6], acc); acc = fmaf(w[7], r[7], acc);
            h = precise_tanh(acc);       // lanes 5..7 stay exactly 0

            // one swizzle set of h_new: feeds fc1 now and the dot next step
            r[0] = h;
            r[1] = SWZF(h, XOR1); r[2] = SWZF(h, XOR2); r[3] = SWZF(h, XOR3);
            r[4] = SWZF(h, XOR4); r[5] = SWZF(h, XOR5); r[6] = SWZF(h, XOR6);
            r[7] = SWZF(h, XOR7);

            // fc1 row j + relu
            float g = fb;
            g = fmaf(f[0], r[0], g); g = fmaf(f[1], r[1], g);
            g = fmaf(f[2], r[2], g); g = fmaf(f[3], r[3], g);
            g = fmaf(f[4], r[4], g); g = fmaf(f[5], r[5], g);
            g = fmaf(f[6], r[6], g); g = fmaf(f[7], r[7], g);
            const float hid = fmaxf(g, 0.0f);

            // fc2: butterfly sum over the 8-lane group (padded lanes add 0)
            float p = hid * w2;
            p += SWZF(p, XOR1);
            p += SWZF(p, XOR2);
            p += SWZF(p, XOR4);
            const float y = p + b2;
            if (u == 0) y0 = y; else if (u == 1) y1 = y; else if (u == 2) y2 = y; else y3 = y;
        }
        if (j == 0) {
            *reinterpret_cast<float4*>(yrow + t) = make_float4(y0, y1, y2, y3);
        }
    }
}

extern "C" void kernel_launch(void* const* d_in, const int* in_sizes, int n_in,
                              void* d_out, int out_size, void* d_ws, size_t ws_size,
                              hipStream_t stream)
{
    const float* hidden = (const float*)d_in[0];
    const float* X      = (const float*)d_in[1];
    const float* W_ih   = (const float*)d_in[2];
    const float* W_hh   = (const float*)d_in[3];
    const float* b_ih   = (const float*)d_in[4];
    const float* b_hh   = (const float*)d_in[5];
    const float* fc1_w  = (const float*)d_in[6];
    const float* fc1_b  = (const float*)d_in[7];
    const float* fc2_w  = (const float*)d_in[8];
    const float* fc2_b  = (const float*)d_in[9];
    float* out = (float*)d_out;

    // 4096 batch elements * 8 lanes = 32768 threads; 64-thread (1-wave) blocks.
    wavernn_kernel<<<dim3(B_ * 8 / 64), dim3(64), 0, stream>>>(
        hidden, X, W_ih, W_hh, b_ih, b_hh, fc1_w, fc1_b, fc2_w, fc2_b, out);
}

// Round 7
// 352.102 us; speedup vs baseline: 1.2499x; 1.2499x over previous
//
#include <hip/hip_runtime.h>
#include <math.h>

// WaveRNN: B=4096, T=2048, H=5 tanh RNN + fc1(5x5)+relu + fc2(1x5), fused.
// One batch element per 8-lane group (H padded 5->8); lane j owns h_j.
// Round 6 (ds_swizzle version): PASS, absmax 0.0293, 440us, VALUBusy 16% ->
// latency-bound on the LDS pipe (11 swizzles/step, ~30-60cy each, in-order
// lgkmcnt). This round: identical arithmetic, but ALL cross-lane exchange via
// DPP (quad_perm / row_half_mirror), ~2cy VALU latency, no LDS ops at all.
// Lane permutes are bit-exact -> absmax must stay exactly 0.0293.

#define B_ 4096
#define T_ 2048

// DPP: result[l] = src[perm(l)] within controls; all lanes active.
#define DPPF(v, ctrl) __int_as_float(__builtin_amdgcn_update_dpp(0, __float_as_int(v), (ctrl), 0xF, 0xF, true))
#define QP_X1 0xB1   // quad_perm [1,0,3,2]  : lane l <- l^1
#define QP_X2 0x4E   // quad_perm [2,3,0,1]  : lane l <- l^2
#define QP_X3 0x1B   // quad_perm [3,2,1,0]  : lane l <- l^3
#define RHM   0x141  // row_half_mirror      : lane l <- l^7 (within 8)

__device__ __forceinline__ float precise_tanh(float x) {
    // tanh(x) = 1 - 2/(exp2(2x*log2e)+1), compensated argument +
    // Newton-refined rcp; ~1.5e-7 abs error, branchless, clamp keeps finite.
    const float L_hi = 1.44269504f;
    const float L_lo = 1.9259630e-8f;
    const float LN2  = 0.69314718f;

    float xc = fminf(fmaxf(x, -15.0f), 15.0f);
    float y2 = xc + xc;
    float a  = y2 * L_hi;
    float dl = fmaf(y2, L_hi, -a);
    dl = fmaf(y2, L_lo, dl);
    float e0 = __builtin_amdgcn_exp2f(a);
    float e  = fmaf(e0, dl * LN2, e0);
    float d  = e + 1.0f;
    float r0 = __builtin_amdgcn_rcpf(d);
    float r  = fmaf(fmaf(-d, r0, 1.0f), r0, r0);
    return fmaf(-2.0f, r, 1.0f);
}

// r[k] = h from lane j^k, all via DPP (depth 2, VALU pipe only).
#define EXCHANGE(rr, hh)                                   \
    do {                                                   \
        rr[0] = (hh);                                      \
        rr[1] = DPPF((hh), QP_X1);                         \
        rr[2] = DPPF((hh), QP_X2);                         \
        rr[3] = DPPF((hh), QP_X3);                         \
        rr[7] = DPPF((hh), RHM);                           \
        rr[6] = DPPF(rr[7], QP_X1);                        \
        rr[5] = DPPF(rr[7], QP_X2);                        \
        rr[4] = DPPF(rr[7], QP_X3);                        \
    } while (0)

__global__ __launch_bounds__(64, 1) void wavernn_kernel(
    const float* __restrict__ hidden, const float* __restrict__ X,
    const float* __restrict__ W_ih, const float* __restrict__ W_hh,
    const float* __restrict__ b_ih, const float* __restrict__ b_hh,
    const float* __restrict__ fc1_w, const float* __restrict__ fc1_b,
    const float* __restrict__ fc2_w, const float* __restrict__ fc2_b,
    float* __restrict__ out)
{
    const int lane = threadIdx.x;                    // 0..63
    const int j = lane & 7;                          // position in 8-lane group
    const int grp = (blockIdx.x * 64 + lane) >> 3;   // batch element, 0..4095

    float w[8], f[8];
#pragma unroll
    for (int k = 0; k < 8; ++k) {
        const int c = j ^ k;
        const bool live = (j < 5) && (c < 5);
        w[k] = live ? W_hh[j * 5 + c] : 0.0f;
        f[k] = live ? fc1_w[j * 5 + c] : 0.0f;
    }
    const float wih  = (j < 5) ? W_ih[j] : 0.0f;
    const float bias = (j < 5) ? (b_ih[j] + b_hh[j]) : 0.0f;
    const float fb   = (j < 5) ? fc1_b[j] : 0.0f;
    const float w2   = (j < 5) ? fc2_w[j] : 0.0f;
    const float b2   = fc2_b[0];

    float h = (j < 5) ? hidden[grp * 5 + j] : 0.0f;

    float r[8];
    EXCHANGE(r, h);

    const float* __restrict__ xrow = X  + (size_t)grp * T_;
    float*       __restrict__ yrow = out + (size_t)grp * T_;

    for (int t = 0; t < T_; t += 4) {
        const float4 x4 = *reinterpret_cast<const float4*>(xrow + t);
        float y0, y1, y2, y3;
#pragma unroll
        for (int u = 0; u < 4; ++u) {
            const float x = (u == 0) ? x4.x : (u == 1) ? x4.y : (u == 2) ? x4.z : x4.w;

            // acc = x*W_ih[j] + (b_ih+b_hh)[j] + sum_c W_hh[j][c]*h_prev[c]
            // (same fma order as the passing round-6 kernel -> bit-identical)
            float acc = fmaf(x, wih, bias);
            acc = fmaf(w[0], r[0], acc); acc = fmaf(w[1], r[1], acc);
            acc = fmaf(w[2], r[2], acc); acc = fmaf(w[3], r[3], acc);
            acc = fmaf(w[4], r[4], acc); acc = fmaf(w[5], r[5], acc);
            acc = fmaf(w[6], r[6], acc); acc = fmaf(w[7], r[7], acc);
            h = precise_tanh(acc);       // lanes 5..7 stay exactly 0

            EXCHANGE(r, h);              // feeds fc1 now and the dot next step

            // fc1 row j + relu
            float g = fb;
            g = fmaf(f[0], r[0], g); g = fmaf(f[1], r[1], g);
            g = fmaf(f[2], r[2], g); g = fmaf(f[3], r[3], g);
            g = fmaf(f[4], r[4], g); g = fmaf(f[5], r[5], g);
            g = fmaf(f[6], r[6], g); g = fmaf(f[7], r[7], g);
            const float hid = fmaxf(g, 0.0f);

            // fc2: 8-lane butterfly. After XOR1+XOR2 stages p is quad-uniform,
            // so the l^7 (RHM) partner equals the l^4 partner -> bit-identical
            // to the swizzle XOR4 version.
            float p = hid * w2;
            p += DPPF(p, QP_X1);
            p += DPPF(p, QP_X2);
            p += DPPF(p, RHM);
            const float y = p + b2;
            if (u == 0) y0 = y; else if (u == 1) y1 = y; else if (u == 2) y2 = y; else y3 = y;
        }
        if (j == 0) {
            *reinterpret_cast<float4*>(yrow + t) = make_float4(y0, y1, y2, y3);
        }
    }
}

extern "C" void kernel_launch(void* const* d_in, const int* in_sizes, int n_in,
                              void* d_out, int out_size, void* d_ws, size_t ws_size,
                              hipStream_t stream)
{
    const float* hidden = (const float*)d_in[0];
    const float* X      = (const float*)d_in[1];
    const float* W_ih   = (const float*)d_in[2];
    const float* W_hh   = (const float*)d_in[3];
    const float* b_ih   = (const float*)d_in[4];
    const float* b_hh   = (const float*)d_in[5];
    const float* fc1_w  = (const float*)d_in[6];
    const float* fc1_b  = (const float*)d_in[7];
    const float* fc2_w  = (const float*)d_in[8];
    const float* fc2_b  = (const float*)d_in[9];
    float* out = (float*)d_out;

    wavernn_kernel<<<dim3(B_ * 8 / 64), dim3(64), 0, stream>>>(
        hidden, X, W_ih, W_hh, b_ih, b_hh, fc1_w, fc1_b, fc2_w, fc2_b, out);
}